// Round 24
// baseline (123.739 us; speedup 1.0000x reference)
//
#include <hip/hip_runtime.h>
#include <hip/hip_bf16.h>
#include <cstdint>
#include <cstddef>

typedef unsigned short u16;
typedef unsigned int u32;
typedef __attribute__((ext_vector_type(8))) short short8v;   // 8 bf16 MFMA frag
typedef __attribute__((ext_vector_type(4))) float f32x4;     // MFMA accumulator
typedef __attribute__((ext_vector_type(4))) u16 u16x4;
typedef __attribute__((ext_vector_type(8))) u16 u16x8;

// Problem constants
static constexpr int Bc = 2, Tc = 2048, Dc = 1024, Hc = 16, HKVc = 4, HDc = 64;
static constexpr int Mc = Bc * Tc;                 // 4096 rows
static constexpr float EPSc = 1.1920929e-07f;

// ---- split-K chunk tables (perfect per-CU balance, verified r21) ----
__constant__ int C_QT[24] = {15,7,14,14,13,12,11,10, 15,13,12,10,9,8,11,8, 0,1,2,3,4,5,9,6};
__constant__ int C_S0[24] = {0,0,0,15,14,13,0,11, 16,0,0,0,0,0,12,9, 0,0,0,0,0,0,10,0};
__constant__ int C_NS[24] = {16,16,15,15,14,13,12,11, 16,14,13,11,10,9,12,9, 2,4,6,8,10,12,10,14};
__constant__ int C_MF[32] = {16,16, 17,17, 18,18, 19,19, 20,20, 21,21, 23,23, 1,1,
                             13,15, 12,22, 11,7, 6,14, 10,5, 9,4, 2,3, 0,8};

static __device__ __forceinline__ u16 f2bf(float f) {
  u32 u = __builtin_bit_cast(u32, f);
  return (u16)((u + 0x7fffu + ((u >> 16) & 1u)) >> 16);
}
static __device__ __forceinline__ float bf2f(u16 b) {
  u32 u = ((u32)b) << 16;
  return __builtin_bit_cast(float, u);
}
static __device__ __forceinline__ float fast_exp2(float x) {
  float r;
  asm("v_exp_f32 %0, %1" : "=v"(r) : "v"(x));
  return r;
}
static __device__ __forceinline__ u32 cvt_pk_bf16(float lo, float hi) {
  u32 r;
  asm("v_cvt_pk_bf16_f32 %0, %1, %2" : "=v"(r) : "v"(lo), "v"(hi));
  return r;
}
// direct global->LDS 16B DMA; LDS dest = wave-uniform base + lane*16 (linear)
static __device__ __forceinline__ void gload_lds16(const u16* g, u16* l) {
  __builtin_amdgcn_global_load_lds(
      (const __attribute__((address_space(1))) u32*)g,
      (__attribute__((address_space(3))) u32*)l, 16, 0, 0);
}

// ---------------- numpy-exact fp32 pairwise abs-mean (verified round 3/7) ----------------
__global__ __launch_bounds__(256) void np_leafsum_all(const float* __restrict__ q_w,
                                                      const float* __restrict__ k_w,
                                                      const float* __restrict__ o_w,
                                                      float* __restrict__ leaf) {
  int blk = blockIdx.x;
  const float* w;
  float* out;
  int lfbase;
  if (blk < 256)      { w = q_w; out = leaf;         lfbase = blk * 32; }
  else if (blk < 320) { w = k_w; out = leaf + 8192;  lfbase = (blk - 256) * 32; }
  else                { w = o_w; out = leaf + 10240; lfbase = (blk - 320) * 32; }
  int t = threadIdx.x;
  int lf = lfbase + (t >> 3), j = t & 7;
  const float* a = w + (size_t)lf * 128;
  float r = fabsf(a[j]);
#pragma unroll
  for (int i = 8; i < 128; i += 8) r += fabsf(a[i + j]);
  float x = r + __shfl_xor(r, 1);
  float y = x + __shfl_xor(x, 2);
  float z = y + __shfl_xor(y, 4);
  if (j == 0) out[lf] = z;
}

__global__ __launch_bounds__(256) void np_treemean3(const float* __restrict__ leaf,
                                                    float* __restrict__ th) {
  int m = blockIdx.x;
  const float* src = leaf + (m == 0 ? 0 : (m == 1 ? 8192 : 10240));
  int nle = (m == 1) ? 2048 : 8192;
  float inv_n = (m == 1) ? (1.0f / 262144.0f) : (1.0f / 1048576.0f);
  int t = threadIdx.x;
  int chunk = nle >> 8;                      // 32 or 8, power of two
  float v[32];
  for (int i = 0; i < chunk; i += 4) {
    float4 f = *(const float4*)&src[t * chunk + i];
    v[i] = f.x; v[i + 1] = f.y; v[i + 2] = f.z; v[i + 3] = f.w;
  }
  for (int cnt = chunk >> 1; cnt >= 1; cnt >>= 1)
    for (int i = 0; i < cnt; ++i) v[i] = v[2 * i] + v[2 * i + 1];
  float s = v[0];
#pragma unroll
  for (int off = 1; off < 64; off <<= 1) s += __shfl_xor(s, off);
  __shared__ float red[4];
  if ((t & 63) == 0) red[t >> 6] = s;
  __syncthreads();
  if (t == 0) th[m] = ((red[0] + red[1]) + (red[2] + red[3])) * inv_n;
}

// ---------------- fused prep: ternary quantize + v_w cast + RMSNorm hi/lo splits ----------
__global__ __launch_bounds__(256) void prep_mega(const float* __restrict__ q_w,
                                                 const float* __restrict__ k_w,
                                                 const float* __restrict__ o_w,
                                                 const float* __restrict__ v_w,
                                                 const float* __restrict__ th,
                                                 u16* __restrict__ Wq,
                                                 u16* __restrict__ Wk,
                                                 u16* __restrict__ Wo,
                                                 u16* __restrict__ Vwh,
                                                 const float* __restrict__ X,
                                                 const float* __restrict__ g1,
                                                 const float* __restrict__ g2,
                                                 u16* __restrict__ H1, u16* __restrict__ L1,
                                                 u16* __restrict__ H2, u16* __restrict__ L2,
                                                 u16* __restrict__ HV) {
  __shared__ float red[4];
  int blk = blockIdx.x;
  int tid = threadIdx.x;
  if (blk < 2560) {
    int i4 = blk * 256 + tid;                  // float4 index
    if (i4 < 589824) {
      const float* w; u16* o; float t;
      int j;
      if (i4 < 262144)      { w = q_w; o = Wq; t = th[0]; j = i4; }
      else if (i4 < 327680) { w = k_w; o = Wk; t = th[1]; j = i4 - 262144; }
      else                  { w = o_w; o = Wo; t = th[2]; j = i4 - 327680; }
      float4 v = *(const float4*)&w[(size_t)j * 4];
      float y[4] = {v.x, v.y, v.z, v.w};
      u16x4 q;
#pragma unroll
      for (int c = 0; c < 4; ++c)
        q[c] = (y[c] > t) ? (u16)0x3F80 : ((y[c] < -t) ? (u16)0xBF80 : (u16)0);
      *(u16x4*)&o[(size_t)j * 4] = q;
    } else {
      int j = i4 - 589824;                     // v_w float4 index, [0, 65536)
      float4 v = *(const float4*)&v_w[(size_t)j * 4];
      float y[4] = {v.x, v.y, v.z, v.w};
      u16x4 h;
#pragma unroll
      for (int c = 0; c < 4; ++c) h[c] = f2bf(y[c]);
      *(u16x4*)&Vwh[(size_t)j * 4] = h;
    }
    return;
  }
  int row = blk - 2560;
  const float* xr = X + (size_t)row * Dc;
  float4 v = *(const float4*)&xr[tid * 4];
  float vv[4] = {v.x, v.y, v.z, v.w};
  {
    u16x4 h;
#pragma unroll
    for (int j = 0; j < 4; ++j) h[j] = f2bf(vv[j]);
    *(u16x4*)&HV[(size_t)row * Dc + tid * 4] = h;
  }
  float ss = v.x * v.x + v.y * v.y + v.z * v.z + v.w * v.w;
#pragma unroll
  for (int off = 1; off < 64; off <<= 1) ss += __shfl_xor(ss, off);
  if ((tid & 63) == 0) red[tid >> 6] = ss;
  __syncthreads();
  float tot = red[0] + red[1] + red[2] + red[3];
  float inv = 1.0f / sqrtf(tot * (1.0f / (float)Dc) + EPSc);
  {
    float4 a = *(const float4*)&g1[tid * 4];
    float ga[4] = {a.x, a.y, a.z, a.w};
    u16x4 h, l;
#pragma unroll
    for (int j = 0; j < 4; ++j) {
      float y = vv[j] * inv * ga[j];
      u16 hb = f2bf(y);
      h[j] = hb;
      l[j] = f2bf(y - bf2f(hb));
    }
    *(u16x4*)&H1[(size_t)row * Dc + tid * 4] = h;
    *(u16x4*)&L1[(size_t)row * Dc + tid * 4] = l;
  }
  {
    float4 a = *(const float4*)&g2[tid * 4];
    float ga[4] = {a.x, a.y, a.z, a.w};
    u16x4 h, l;
#pragma unroll
    for (int j = 0; j < 4; ++j) {
      float y = vv[j] * inv * ga[j];
      u16 hb = f2bf(y);
      h[j] = hb;
      l[j] = f2bf(y - bf2f(hb));
    }
    *(u16x4*)&H2[(size_t)row * Dc + tid * 4] = h;
    *(u16x4*)&L2[(size_t)row * Dc + tid * 4] = l;
  }
}

// ---------------- shared GEMM body, templated tile (r9-r15 shape, verified) ----------------
// BM=MF*32 x BN=NF*32 tile, BK=64, 4 waves (2x2), wave tile (BM/2)x(BN/2).
// MODE 0: C fp32.  MODE 1: O1/O2 = bf16 hi/lo.  MODE 3: O1 = bf16, cols permuted
// within each 32-block by gp(k) (attn P slot order).  LDS: AhS | [AlS] | BhS.
template <bool PA, int MODE, int MF, int NF>
static __device__ __forceinline__ void gemm_body(
    const u16* __restrict__ Ah, const u16* __restrict__ Al,
    const u16* __restrict__ Bh,
    int N, int K, int bm, int bn,
    float* __restrict__ C, u16* __restrict__ O1, u16* __restrict__ O2,
    u16* smem) {
  constexpr int BM = MF * 32, BN = NF * 32;
  constexpr int APT = BM / 32, BPT = BN / 32;
  u16* AhS = smem;
  u16* AlS = smem + BM * 64;
  u16* BhS = smem + (PA ? 2 : 1) * BM * 64;
  int tid = threadIdx.x;
  int l = tid & 63, w = tid >> 6;
  int wm = (w >> 1) * (BM / 2), wn = (w & 1) * (BN / 2);
  u16x8 rAh[APT], rAl[PA ? APT : 1], rBh[BPT];
  f32x4 acc[MF][NF] = {};
#define LOADTILE(kb_)                                                               \
  {                                                                                 \
    _Pragma("unroll") for (int p = 0; p < APT; ++p) {                               \
      int idx = tid + p * 256;                                                      \
      int row = idx >> 3, cc = idx & 7;                                             \
      rAh[p] = *(const u16x8*)&Ah[(size_t)(bm + row) * K + (kb_) + cc * 8];         \
      if (PA) rAl[p] = *(const u16x8*)&Al[(size_t)(bm + row) * K + (kb_) + cc * 8]; \
    }                                                                               \
    _Pragma("unroll") for (int p = 0; p < BPT; ++p) {                               \
      int idx = tid + p * 256;                                                      \
      int row = idx >> 3, cc = idx & 7;                                             \
      rBh[p] = *(const u16x8*)&Bh[(size_t)(bn + row) * K + (kb_) + cc * 8];         \
    }                                                                               \
  }
  LOADTILE(0)
  for (int kb = 0; kb < K; kb += 64) {
    __syncthreads();
#pragma unroll
    for (int p = 0; p < APT; ++p) {
      int idx = tid + p * 256;
      int row = idx >> 3, cc = idx & 7;
      int off = row * 64 + ((cc * 8) ^ ((row & 7) << 3));
      *(u16x8*)&AhS[off] = rAh[p];
      if (PA) *(u16x8*)&AlS[off] = rAl[p];
    }
#pragma unroll
    for (int p = 0; p < BPT; ++p) {
      int idx = tid + p * 256;
      int row = idx >> 3, cc = idx & 7;
      int off = row * 64 + ((cc * 8) ^ ((row & 7) << 3));
      *(u16x8*)&BhS[off] = rBh[p];
    }
    if (kb + 64 < K) LOADTILE(kb + 64)
    __syncthreads();
    __builtin_amdgcn_s_setprio(1);
#pragma unroll
    for (int sl = 0; sl < 2; ++sl) {
      short8v fa[MF], fal[MF], fb[NF];
      int kof = (l >> 4) * 8 + sl * 32;
#pragma unroll
      for (int m = 0; m < MF; ++m) {
        int row = wm + m * 16 + (l & 15);
        int off = row * 64 + (kof ^ ((row & 7) << 3));
        fa[m] = *(const short8v*)&AhS[off];
        if (PA) fal[m] = *(const short8v*)&AlS[off];
      }
#pragma unroll
      for (int n = 0; n < NF; ++n) {
        int row = wn + n * 16 + (l & 15);
        int off = row * 64 + (kof ^ ((row & 7) << 3));
        fb[n] = *(const short8v*)&BhS[off];
      }
#pragma unroll
      for (int m = 0; m < MF; ++m)
#pragma unroll
        for (int n = 0; n < NF; ++n) {
          acc[m][n] = __builtin_amdgcn_mfma_f32_16x16x32_bf16(fa[m], fb[n], acc[m][n], 0, 0, 0);
          if (PA)
            acc[m][n] = __builtin_amdgcn_mfma_f32_16x16x32_bf16(fal[m], fb[n], acc[m][n], 0, 0, 0);
        }
    }
    __builtin_amdgcn_s_setprio(0);
  }
#undef LOADTILE
#pragma unroll
  for (int m = 0; m < MF; ++m)
#pragma unroll
    for (int n = 0; n < NF; ++n)
#pragma unroll
      for (int r = 0; r < 4; ++r) {
        int grow = bm + wm + m * 16 + (l >> 4) * 4 + r;
        int gcol = bn + wn + n * 16 + (l & 15);
        float v = acc[m][n][r];
        if (MODE == 0) {
          C[(size_t)grow * N + gcol] = v;
        } else if (MODE == 1) {
          u16 hb = f2bf(v);
          O1[(size_t)grow * N + gcol] = hb;
          O2[(size_t)grow * N + gcol] = f2bf(v - bf2f(hb));
        } else {
          int k = gcol & 31;
          int gp = (gcol & ~31) | (((k >> 2) & 3) << 3) |
                   (((k >> 4) & 1) << 2) | (k & 3);
          O1[(size_t)grow * N + gp] = f2bf(v);
        }
      }
}

// ---------------- fused QKV projections: 512 blocks (2/CU), Q at 128x128 ----------------
// [0,256): Q 128x128 2-pass (48KB LDS).  [256,384): K 64x128 2-pass.
// [384,512): V 64x128 1-pass, Vt slot-permuted.
__global__ __launch_bounds__(256, 1) void qkv_mega(
    const u16* __restrict__ Xqh, const u16* __restrict__ Xql, const u16* __restrict__ Wq,
    const u16* __restrict__ Xkh, const u16* __restrict__ Xkl, const u16* __restrict__ Wk,
    const u16* __restrict__ Xvh, const u16* __restrict__ Vwh,
    u16* __restrict__ Qh, u16* __restrict__ Ql,
    u16* __restrict__ Kh, u16* __restrict__ Kl,
    u16* __restrict__ Vt) {
  __shared__ __align__(16) u16 SMEM[24576];   // 48KB
  int bx = blockIdx.x;
  if (bx < 256) {
    int bm = (bx >> 3) * 128, bn = (bx & 7) * 128;
    gemm_body<true, 1, 4, 4>(Xqh, Xql, Wq, 1024, 1024, bm, bn, nullptr, Qh, Ql, SMEM);
  } else if (bx < 384) {
    int t = bx - 256;
    int bm = (t >> 1) * 64, bn = (t & 1) * 128;
    gemm_body<true, 1, 2, 4>(Xkh, Xkl, Wk, 256, 1024, bm, bn, nullptr, Kh, Kl, SMEM);
  } else {
    int t = bx - 384;
    int bm = (t >> 5) * 64, bn = (t & 31) * 128;
    gemm_body<false, 3, 2, 4>(Vwh, nullptr, Xvh, 4096, 1024, bm, bn, nullptr, Vt, nullptr, SMEM);
  }
}

// ---------------- O-projection GEMM: 128x128 tile (256 blocks, 32KB) ----------------
__global__ __launch_bounds__(256, 1) void o_gemm(
    const u16* __restrict__ Ah, const u16* __restrict__ Bh,
    float* __restrict__ C) {
  __shared__ __align__(16) u16 SMEM[16384];   // 32KB (1-pass)
  int bm = blockIdx.y * 128, bn = blockIdx.x * 128;
  gemm_body<false, 0, 4, 4>(Ah, nullptr, Bh, 1024, 1024, bm, bn, C, nullptr, nullptr, SMEM);
}

// ---------------- split-K attention PHASE 1 (unchanged from r23, verified) ----------------
__global__ __launch_bounds__(256, 3) void attn_part(
    const u16* __restrict__ Qh, const u16* __restrict__ Ql,
    const u16* __restrict__ Kh, const u16* __restrict__ Kl,
    const u16* __restrict__ Vt,
    const float* __restrict__ qk_gain,
    u16* __restrict__ Opart, float* __restrict__ MLpart) {
  __shared__ __align__(16) u16 SM[24576];   // 2 x (Kh|Kl|Vt 4096 u16 each) = 48KB
  int tid = threadIdx.x;
  int w = tid >> 6, l = tid & 63;
  int hb = blockIdx.x;
  int h = hb & 15, b = hb >> 4;
  int kvh = h >> 2;
  int f = blockIdx.y;                 // 0..23
  int qt = C_QT[f];
  int s0 = C_S0[f];
  int s1 = s0 + C_NS[f];
  int q0 = qt * 128;
  const float sc2 = qk_gain[0] * 0.125f * 1.44269504f;
  const float thr = 8.0f / sc2;       // defer-max threshold (P <= 2^8)
#define GLOADTILE(K0, BI)                                                       \
  {                                                                             \
    u16* bb = SM + (BI) * 12288;                                                \
    _Pragma("unroll") for (int p = 0; p < 2; ++p) {                             \
      int idx = tid + p * 256;                                                  \
      int jj = idx >> 3;                                                        \
      int cc = (idx & 7) ^ (jj & 7);                                            \
      size_t kb = ((size_t)(b * Tc + (K0) + jj)) * (HKVc * HDc) + kvh * 64 + cc * 8; \
      size_t vb = ((size_t)(kvh * 64 + jj)) * (size_t)Mc + b * Tc + (K0) + cc * 8;   \
      u16* l0 = bb + (w * 64 + p * 256) * 8;                                    \
      gload_lds16(&Kh[kb], l0);                                                 \
      gload_lds16(&Kl[kb], l0 + 4096);                                          \
      gload_lds16(&Vt[vb], l0 + 8192);                                          \
    }                                                                           \
  }
  short8v qb_h[4], qb_l[4];
#pragma unroll
  for (int qp = 0; qp < 2; ++qp) {
    size_t qrow = (size_t)(b * Tc + q0 + w * 32 + qp * 16 + (l & 15));
#pragma unroll
    for (int sl = 0; sl < 2; ++sl) {
      int dstart = (l >> 4) * 8 + sl * 32;
      qb_h[qp * 2 + sl] = *(const short8v*)&Qh[qrow * Dc + h * 64 + dstart];
      qb_l[qp * 2 + sl] = *(const short8v*)&Ql[qrow * Dc + h * 64 + dstart];
    }
  }
  f32x4 Oacc[8] = {{0,0,0,0},{0,0,0,0},{0,0,0,0},{0,0,0,0},
                   {0,0,0,0},{0,0,0,0},{0,0,0,0},{0,0,0,0}};
  float mrow[2] = {-3.0e38f, -3.0e38f};
  float lrow[2] = {0.f, 0.f};
  int qmax_w = q0 + w * 32 + 31;
  GLOADTILE(s0 * 64, 0)
  GLOADTILE((s0 + 1) * 64, 1)
  __syncthreads();
  for (int li = 0; li < s1 - s0; ++li) {
    int stp = s0 + li;
    int k0 = stp * 64;
    u16* Kh_s = SM + (li & 1) * 12288;
    u16* Kl_s = Kh_s + 4096;
    u16* Vt_s = Kh_s + 8192;
    if (k0 <= qmax_w) {
      f32x4 s[8] = {{0,0,0,0},{0,0,0,0},{0,0,0,0},{0,0,0,0},
                    {0,0,0,0},{0,0,0,0},{0,0,0,0},{0,0,0,0}};
      __builtin_amdgcn_s_setprio(1);
#pragma unroll
      for (int kt = 0; kt < 4; ++kt) {
        int key = kt * 16 + (l & 15);
#pragma unroll
        for (int sl = 0; sl < 2; ++sl) {
          int dstart = ((l >> 4) * 8 + 32 * sl) ^ ((key & 7) << 3);
          short8v bh = *(const short8v*)&Kh_s[key * 64 + dstart];
          short8v bl = *(const short8v*)&Kl_s[key * 64 + dstart];
#pragma unroll
          for (int qp = 0; qp < 2; ++qp) {
            s[qp * 4 + kt] = __builtin_amdgcn_mfma_f32_16x16x32_bf16(bh, qb_h[qp * 2 + sl], s[qp * 4 + kt], 0, 0, 0);
            s[qp * 4 + kt] = __builtin_amdgcn_mfma_f32_16x16x32_bf16(bl, qb_h[qp * 2 + sl], s[qp * 4 + kt], 0, 0, 0);
            s[qp * 4 + kt] = __builtin_amdgcn_mfma_f32_16x16x32_bf16(bh, qb_l[qp * 2 + sl], s[qp * 4 + kt], 0, 0, 0);
          }
        }
      }
      __builtin_amdgcn_s_setprio(0);
      bool full = (k0 + 63) <= (q0 + w * 32);
      if (!full) {
#pragma unroll
        for (int qp = 0; qp < 2; ++qp) {
          int qg = q0 + w * 32 + qp * 16 + (l & 15);
#pragma unroll
          for (int kt = 0; kt < 4; ++kt)
#pragma unroll
            for (int r = 0; r < 4; ++r)
              if (k0 + kt * 16 + ((l >> 4) << 2) + r > qg) s[qp * 4 + kt][r] = -3.0e38f;
        }
      }
      float p[2][4][4];
#pragma unroll
      for (int qp = 0; qp < 2; ++qp) {
        float mk[4];
#pragma unroll
        for (int kt = 0; kt < 4; ++kt)
          mk[kt] = fmaxf(fmaxf(s[qp * 4 + kt][0], s[qp * 4 + kt][1]),
                         fmaxf(s[qp * 4 + kt][2], s[qp * 4 + kt][3]));
        float mx = fmaxf(fmaxf(mk[0], mk[1]), fmaxf(mk[2], mk[3]));
        mx = fmaxf(mx, __shfl_xor(mx, 16));
        mx = fmaxf(mx, __shfl_xor(mx, 32));
        if (!__all(mx - mrow[qp] <= thr)) {
          float mnew = fmaxf(mrow[qp], mx);
          float corr = fast_exp2((mrow[qp] - mnew) * sc2);
          mrow[qp] = mnew;
          lrow[qp] *= corr;
#pragma unroll
          for (int dt = 0; dt < 4; ++dt) Oacc[qp * 4 + dt] *= corr;
        }
        float msc = mrow[qp] * sc2;
        float sk[4];
#pragma unroll
        for (int kt = 0; kt < 4; ++kt) {
#pragma unroll
          for (int r = 0; r < 4; ++r)
            p[qp][kt][r] = fast_exp2(__builtin_fmaf(s[qp * 4 + kt][r], sc2, -msc));
          sk[kt] = (p[qp][kt][0] + p[qp][kt][1]) + (p[qp][kt][2] + p[qp][kt][3]);
        }
        float rs = (sk[0] + sk[1]) + (sk[2] + sk[3]);
        rs += __shfl_xor(rs, 16);
        rs += __shfl_xor(rs, 32);
        lrow[qp] += rs;
      }
      short8v fbv[4];
#pragma unroll
      for (int qp = 0; qp < 2; ++qp)
#pragma unroll
        for (int sl = 0; sl < 2; ++sl) {
          union { u32 u[4]; short8v v; } fq;
          fq.u[0] = cvt_pk_bf16(p[qp][2 * sl][0], p[qp][2 * sl][1]);
          fq.u[1] = cvt_pk_bf16(p[qp][2 * sl][2], p[qp][2 * sl][3]);
          fq.u[2] = cvt_pk_bf16(p[qp][2 * sl + 1][0], p[qp][2 * sl + 1][1]);
          fq.u[3] = cvt_pk_bf16(p[qp][2 * sl + 1][2], p[qp][2 * sl + 1][3]);
          fbv[qp * 2 + sl] = fq.v;
        }
      __builtin_amdgcn_s_setprio(1);
#pragma unroll
      for (int dt = 0; dt < 4; ++dt) {
        int d = dt * 16 + (l & 15);
#pragma unroll
        for (int sl = 0; sl < 2; ++sl) {
          int kstart = ((l >> 4) * 8 + 32 * sl) ^ ((d & 7) << 3);
          short8v fav = *(const short8v*)&Vt_s[d * 64 + kstart];
#pragma unroll
          for (int qp = 0; qp < 2; ++qp)
            Oacc[qp * 4 + dt] = __builtin_amdgcn_mfma_f32_16x16x32_bf16(fav, fbv[qp * 2 + sl], Oacc[qp * 4 + dt], 0, 0, 0);
        }
      }
      __builtin_amdgcn_s_setprio(0);
    }
    __syncthreads();   // readers of buf[li&1] done; in-flight DMA drained
    if (stp + 2 < s1) GLOADTILE((stp + 2) * 64, li & 1)
  }
  // epilogue: unnormalized partial O (bf16) + per-q m,l
  int G = hb * 24 + f;
  u16* Op = Opart + (size_t)G * 8192;           // [128 q][64 d]
  float* Es = (float*)SM + w * 1088;            // per-wave [16 q][68 d]
#pragma unroll
  for (int qp = 0; qp < 2; ++qp) {
#pragma unroll
    for (int dt = 0; dt < 4; ++dt)
#pragma unroll
      for (int r = 0; r < 4; ++r)
        Es[(l & 15) * 68 + dt * 16 + ((l >> 4) << 2) + r] = Oacc[qp * 4 + dt][r];
    int qloc = w * 32 + qp * 16 + (l >> 2);
#pragma unroll
    for (int j = 0; j < 4; ++j) {
      float4 vv = *(const float4*)&Es[(l >> 2) * 68 + (l & 3) * 4 + j * 16];
      u16x4 o4;
      o4[0] = f2bf(vv.x); o4[1] = f2bf(vv.y); o4[2] = f2bf(vv.z); o4[3] = f2bf(vv.w);
      *(u16x4*)&Op[qloc * 64 + (l & 3) * 4 + j * 16] = o4;
    }
  }
  if (l < 16) {
#pragma unroll
    for (int qp = 0; qp < 2; ++qp) {
      int qloc = w * 32 + qp * 16 + l;
      MLpart[(size_t)G * 256 + qloc * 2 + 0] = mrow[qp];
      MLpart[(size_t)G * 256 + qloc * 2 + 1] = lrow[qp];
    }
  }
#undef GLOADTILE
}

// ---------------- PHASE 2: fused merge + RMSNorm + o_g scale -> Xoh bf16 ----------------
__global__ __launch_bounds__(256) void merge_rms(const u16* __restrict__ Opart,
                                                 const float* __restrict__ MLpart,
                                                 const float* __restrict__ o_g,
                                                 const float* __restrict__ qk_gain,
                                                 u16* __restrict__ Xoh) {
  const float sc2 = qk_gain[0] * 0.125f * 1.44269504f;
  int t = threadIdx.x;
  int row_i = t >> 6, l = t & 63;
  int rr = blockIdx.x * 4 + row_i;
  int b = rr >> 11, tpos = rr & 2047;
  int qt = tpos >> 7, qloc = tpos & 127;
  int head = l >> 2;
  int hb = b * 16 + head;
  int nc = (qt >= 8) ? 2 : 1;
  size_t G0 = (size_t)hb * 24 + C_MF[qt * 2 + 0];
  size_t G1 = (size_t)hb * 24 + C_MF[qt * 2 + 1];
  float m0 = MLpart[G0 * 256 + qloc * 2 + 0];
  float l0 = MLpart[G0 * 256 + qloc * 2 + 1];
  float m1 = -3.0e38f, l1 = 0.0f;
  if (nc == 2) {
    m1 = MLpart[G1 * 256 + qloc * 2 + 0];
    l1 = MLpart[G1 * 256 + qloc * 2 + 1];
  }
  float M = fmaxf(m0, m1);
  float w0 = fast_exp2((m0 - M) * sc2);
  float w1 = (nc == 2) ? fast_exp2((m1 - M) * sc2) : 0.0f;
  float L = w0 * l0 + w1 * l1;
  int dio = (l & 3) * 16;   // d-offset within head
  const u16* Op0 = Opart + G0 * 8192 + qloc * 64 + dio;
  float val[16];
  {
    u16x8 a0 = *(const u16x8*)&Op0[0];
    u16x8 a1 = *(const u16x8*)&Op0[8];
#pragma unroll
    for (int j = 0; j < 8; ++j) { val[j] = w0 * bf2f(a0[j]); val[8 + j] = w0 * bf2f(a1[j]); }
  }
  if (nc == 2) {
    const u16* Op1 = Opart + G1 * 8192 + qloc * 64 + dio;
    u16x8 a0 = *(const u16x8*)&Op1[0];
    u16x8 a1 = *(const u16x8*)&Op1[8];
#pragma unroll
    for (int j = 0; j < 8; ++j) { val[j] += w1 * bf2f(a0[j]); val[8 + j] += w1 * bf2f(a1[j]); }
  }
  float invL = 1.0f / L;
#pragma unroll
  for (int j = 0; j < 16; ++j) val[j] *= invL;
  float ss = 0.0f;
#pragma unroll
  for (int j = 0; j < 16; ++j) ss += val[j] * val[j];
#pragma unroll
  for (int off = 1; off < 64; off <<= 1) ss += __shfl_xor(ss, off);
  float inv = 1.0f / sqrtf(ss * (1.0f / (float)Dc) + EPSc);
  int col = head * 64 + dio;
  u16x8 h0, h1;
#pragma unroll
  for (int j = 0; j < 8; ++j) {
    h0[j] = f2bf(val[j] * inv * o_g[col + j]);
    h1[j] = f2bf(val[8 + j] * inv * o_g[col + 8 + j]);
  }
  u16* dst = Xoh + (size_t)rr * Dc + col;
  *(u16x8*)&dst[0] = h0;
  *(u16x8*)&dst[8] = h1;
}

// ---------------- launch ----------------
extern "C" void kernel_launch(void* const* d_in, const int* in_sizes, int n_in,
                              void* d_out, int out_size, void* d_ws, size_t ws_size,
                              hipStream_t stream) {
  const float* x    = (const float*)d_in[0];
  const float* q_w  = (const float*)d_in[1];
  const float* q_g  = (const float*)d_in[2];
  const float* k_w  = (const float*)d_in[3];
  const float* k_g  = (const float*)d_in[4];
  const float* v_w  = (const float*)d_in[5];
  const float* o_w  = (const float*)d_in[6];
  const float* o_g  = (const float*)d_in[7];
  const float* qk_g = (const float*)d_in[8];

  // workspace (bytes), peak ~67.1 MB.  Overlay happens-before chain (all launch-ordered):
  //  - Xqh..Xvh (0..40MB) dead after qkv_mega
  //  - Opart (16..28MB) + MLpart (28..29MB) written by attn_part (post-qkv_mega)
  //  - Xoh (0..8MB, over Xqh) written by merge_rms (post-attn_part; disjoint from Opart)
  char* base = (char*)d_ws;
  u16* Xqh = (u16*)(base + (0ull  << 20));       // 8MB
  u16* Xql = (u16*)(base + (8ull  << 20));       // 8MB
  u16* Xkh = (u16*)(base + (16ull << 20));       // 8MB
  u16* Xkl = (u16*)(base + (24ull << 20));       // 8MB
  u16* Xvh = (u16*)(base + (32ull << 20));       // 8MB
  u16* Qh  = (u16*)(base + (40ull << 20));       // 8MB dedicated
  u16* Ql  = (u16*)(base + (48ull << 20));       // 8MB dedicated
  u16* Kh  = (u16*)(base + (56ull << 20));       // 2MB
  u16* Kl  = (u16*)(base + (58ull << 20));       // 2MB
  u16* Vt  = (u16*)(base + (60ull << 20));       // 2MB
  u16* Wq  = (u16*)(base + (62ull << 20));       // 2MB
  u16* Wk  = (u16*)(base + (64ull << 20));       // 0.5MB
  u16* Wo  = (u16*)(base + (64ull << 20) + (512ull << 10));   // 2MB
  u16* Vwh = (u16*)(base + (66ull << 20) + (512ull << 10));   // 0.5MB
  float* leaf = (float*)(base + (67ull << 20));  // 18432 floats
  float* th   = leaf + 18432;                    // 3
  // overlays
  u16*  Opart   = (u16*)(base + (16ull << 20));  // 12MB: 768 chunks x 16KB (over Xkh/half-Xkl)
  float* MLpart = (float*)(base + (28ull << 20));// 768KB (over rest of Xkl)
  u16*  Xoh     = (u16*)base;                    // 8MB over Xqh (dead after qkv_mega)

  // 1) numpy-exact fp32 thresholds
  np_leafsum_all<<<576, 256, 0, stream>>>(q_w, k_w, o_w, leaf);
  np_treemean3<<<3, 256, 0, stream>>>(leaf, th);

  // 2+3) fused prep: ternary quantize + v_w cast + RMSNorm splits (one launch)
  prep_mega<<<6656, 256, 0, stream>>>(q_w, k_w, o_w, v_w, th, Wq, Wk, Wo, Vwh,
                                      x, q_g, k_g, Xqh, Xql, Xkh, Xkl, Xvh);

  // 4) fused Q+K+V projections: 512 blocks, Q at 128x128
  qkv_mega<<<512, 256, 0, stream>>>(Xqh, Xql, Wq, Xkh, Xkl, Wk, Xvh, Vwh,
                                    Qh, Ql, Kh, Kl, Vt);

  // 5) split-K attention: balanced chunks + gload_lds staging + defer-max
  attn_part<<<dim3(32, 24), 256, 0, stream>>>(Qh, Ql, Kh, Kl, Vt, qk_g, Opart, MLpart);

  // 6) fused merge + RMSNorm + o_g -> Xoh bf16
  merge_rms<<<1024, 256, 0, stream>>>(Opart, MLpart, o_g, qk_g, Xoh);

  // 7) output GEMM -> d_out fp32 (128x128 tiles)
  o_gemm<<<dim3(8, 32), 256, 0, stream>>>(Xoh, Wo, (float*)d_out);
}

// Round 26
// 123.069 us; speedup vs baseline: 1.0054x; 1.0054x over previous
//
#include <hip/hip_runtime.h>
#include <hip/hip_bf16.h>
#include <cstdint>
#include <cstddef>

typedef unsigned short u16;
typedef unsigned int u32;
typedef __attribute__((ext_vector_type(8))) short short8v;   // 8 bf16 MFMA frag
typedef __attribute__((ext_vector_type(4))) float f32x4;     // MFMA accumulator
typedef __attribute__((ext_vector_type(4))) u16 u16x4;
typedef __attribute__((ext_vector_type(8))) u16 u16x8;

// Problem constants
static constexpr int Bc = 2, Tc = 2048, Dc = 1024, Hc = 16, HKVc = 4, HDc = 64;
static constexpr int Mc = Bc * Tc;                 // 4096 rows
static constexpr float EPSc = 1.1920929e-07f;

// ---- split-K chunk tables (perfect per-CU balance, verified r21) ----
__constant__ int C_QT[24] = {15,7,14,14,13,12,11,10, 15,13,12,10,9,8,11,8, 0,1,2,3,4,5,9,6};
__constant__ int C_S0[24] = {0,0,0,15,14,13,0,11, 16,0,0,0,0,0,12,9, 0,0,0,0,0,0,10,0};
__constant__ int C_NS[24] = {16,16,15,15,14,13,12,11, 16,14,13,11,10,9,12,9, 2,4,6,8,10,12,10,14};
__constant__ int C_MF[32] = {16,16, 17,17, 18,18, 19,19, 20,20, 21,21, 23,23, 1,1,
                             13,15, 12,22, 11,7, 6,14, 10,5, 9,4, 2,3, 0,8};

static __device__ __forceinline__ u16 f2bf(float f) {
  u32 u = __builtin_bit_cast(u32, f);
  return (u16)((u + 0x7fffu + ((u >> 16) & 1u)) >> 16);
}
static __device__ __forceinline__ float bf2f(u16 b) {
  u32 u = ((u32)b) << 16;
  return __builtin_bit_cast(float, u);
}
static __device__ __forceinline__ float fast_exp2(float x) {
  float r;
  asm("v_exp_f32 %0, %1" : "=v"(r) : "v"(x));
  return r;
}
static __device__ __forceinline__ u32 cvt_pk_bf16(float lo, float hi) {
  u32 r;
  asm("v_cvt_pk_bf16_f32 %0, %1, %2" : "=v"(r) : "v"(lo), "v"(hi));
  return r;
}
// direct global->LDS 16B DMA; LDS dest = wave-uniform base + lane*16 (linear)
static __device__ __forceinline__ void gload_lds16(const u16* g, u16* l) {
  __builtin_amdgcn_global_load_lds(
      (const __attribute__((address_space(1))) u32*)g,
      (__attribute__((address_space(3))) u32*)l, 16, 0, 0);
}

// ---------------- numpy-exact fp32 pairwise abs-mean (verified round 3/7) ----------------
__global__ __launch_bounds__(256) void np_leafsum_all(const float* __restrict__ q_w,
                                                      const float* __restrict__ k_w,
                                                      const float* __restrict__ o_w,
                                                      float* __restrict__ leaf) {
  int blk = blockIdx.x;
  const float* w;
  float* out;
  int lfbase;
  if (blk < 256)      { w = q_w; out = leaf;         lfbase = blk * 32; }
  else if (blk < 320) { w = k_w; out = leaf + 8192;  lfbase = (blk - 256) * 32; }
  else                { w = o_w; out = leaf + 10240; lfbase = (blk - 320) * 32; }
  int t = threadIdx.x;
  int lf = lfbase + (t >> 3), j = t & 7;
  const float* a = w + (size_t)lf * 128;
  float r = fabsf(a[j]);
#pragma unroll
  for (int i = 8; i < 128; i += 8) r += fabsf(a[i + j]);
  float x = r + __shfl_xor(r, 1);
  float y = x + __shfl_xor(x, 2);
  float z = y + __shfl_xor(y, 4);
  if (j == 0) out[lf] = z;
}

__global__ __launch_bounds__(256) void np_treemean3(const float* __restrict__ leaf,
                                                    float* __restrict__ th) {
  int m = blockIdx.x;
  const float* src = leaf + (m == 0 ? 0 : (m == 1 ? 8192 : 10240));
  int nle = (m == 1) ? 2048 : 8192;
  float inv_n = (m == 1) ? (1.0f / 262144.0f) : (1.0f / 1048576.0f);
  int t = threadIdx.x;
  int chunk = nle >> 8;                      // 32 or 8, power of two
  float v[32];
  for (int i = 0; i < chunk; i += 4) {
    float4 f = *(const float4*)&src[t * chunk + i];
    v[i] = f.x; v[i + 1] = f.y; v[i + 2] = f.z; v[i + 3] = f.w;
  }
  for (int cnt = chunk >> 1; cnt >= 1; cnt >>= 1)
    for (int i = 0; i < cnt; ++i) v[i] = v[2 * i] + v[2 * i + 1];
  float s = v[0];
#pragma unroll
  for (int off = 1; off < 64; off <<= 1) s += __shfl_xor(s, off);
  __shared__ float red[4];
  if ((t & 63) == 0) red[t >> 6] = s;
  __syncthreads();
  if (t == 0) th[m] = ((red[0] + red[1]) + (red[2] + red[3])) * inv_n;
}

// ---------------- fused prep: ternary quantize + v_w cast + RMSNorm hi/lo splits ----------
// Blocks [0, 2560): quantize q/k/o + v_w bf16 cast.  Blocks [2560, 6656): RMSNorm rows.
__global__ __launch_bounds__(256) void prep_mega(const float* __restrict__ q_w,
                                                 const float* __restrict__ k_w,
                                                 const float* __restrict__ o_w,
                                                 const float* __restrict__ v_w,
                                                 const float* __restrict__ th,
                                                 u16* __restrict__ Wq,
                                                 u16* __restrict__ Wk,
                                                 u16* __restrict__ Wo,
                                                 u16* __restrict__ Vwh,
                                                 const float* __restrict__ X,
                                                 const float* __restrict__ g1,
                                                 const float* __restrict__ g2,
                                                 u16* __restrict__ H1, u16* __restrict__ L1,
                                                 u16* __restrict__ H2, u16* __restrict__ L2,
                                                 u16* __restrict__ HV) {
  __shared__ float red[4];
  int blk = blockIdx.x;
  int tid = threadIdx.x;
  if (blk < 2560) {
    int i4 = blk * 256 + tid;                  // float4 index
    if (i4 < 589824) {
      const float* w; u16* o; float t;
      int j;
      if (i4 < 262144)      { w = q_w; o = Wq; t = th[0]; j = i4; }
      else if (i4 < 327680) { w = k_w; o = Wk; t = th[1]; j = i4 - 262144; }
      else                  { w = o_w; o = Wo; t = th[2]; j = i4 - 327680; }
      float4 v = *(const float4*)&w[(size_t)j * 4];
      float y[4] = {v.x, v.y, v.z, v.w};
      u16x4 q;
#pragma unroll
      for (int c = 0; c < 4; ++c)
        q[c] = (y[c] > t) ? (u16)0x3F80 : ((y[c] < -t) ? (u16)0xBF80 : (u16)0);
      *(u16x4*)&o[(size_t)j * 4] = q;
    } else {
      int j = i4 - 589824;                     // v_w float4 index, [0, 65536)
      float4 v = *(const float4*)&v_w[(size_t)j * 4];
      float y[4] = {v.x, v.y, v.z, v.w};
      u16x4 h;
#pragma unroll
      for (int c = 0; c < 4; ++c) h[c] = f2bf(y[c]);
      *(u16x4*)&Vwh[(size_t)j * 4] = h;
    }
    return;
  }
  int row = blk - 2560;
  const float* xr = X + (size_t)row * Dc;
  float4 v = *(const float4*)&xr[tid * 4];
  float vv[4] = {v.x, v.y, v.z, v.w};
  {
    u16x4 h;
#pragma unroll
    for (int j = 0; j < 4; ++j) h[j] = f2bf(vv[j]);
    *(u16x4*)&HV[(size_t)row * Dc + tid * 4] = h;
  }
  float ss = v.x * v.x + v.y * v.y + v.z * v.z + v.w * v.w;
#pragma unroll
  for (int off = 1; off < 64; off <<= 1) ss += __shfl_xor(ss, off);
  if ((tid & 63) == 0) red[tid >> 6] = ss;
  __syncthreads();
  float tot = red[0] + red[1] + red[2] + red[3];
  float inv = 1.0f / sqrtf(tot * (1.0f / (float)Dc) + EPSc);
  {
    float4 a = *(const float4*)&g1[tid * 4];
    float ga[4] = {a.x, a.y, a.z, a.w};
    u16x4 h, l;
#pragma unroll
    for (int j = 0; j < 4; ++j) {
      float y = vv[j] * inv * ga[j];
      u16 hb = f2bf(y);
      h[j] = hb;
      l[j] = f2bf(y - bf2f(hb));
    }
    *(u16x4*)&H1[(size_t)row * Dc + tid * 4] = h;
    *(u16x4*)&L1[(size_t)row * Dc + tid * 4] = l;
  }
  {
    float4 a = *(const float4*)&g2[tid * 4];
    float ga[4] = {a.x, a.y, a.z, a.w};
    u16x4 h, l;
#pragma unroll
    for (int j = 0; j < 4; ++j) {
      float y = vv[j] * inv * ga[j];
      u16 hb = f2bf(y);
      h[j] = hb;
      l[j] = f2bf(y - bf2f(hb));
    }
    *(u16x4*)&H2[(size_t)row * Dc + tid * 4] = h;
    *(u16x4*)&L2[(size_t)row * Dc + tid * 4] = l;
  }
}

// ---------------- shared GEMM body (r16, verified): 64x128 tile, BK=64 ----------------
template <bool PA, int MODE>
static __device__ __forceinline__ void gemm_body(
    const u16* __restrict__ Ah, const u16* __restrict__ Al,
    const u16* __restrict__ Bh,
    int N, int K, int bm, int bn,
    float* __restrict__ C, u16* __restrict__ O1, u16* __restrict__ O2,
    u16* smem) {
  constexpr int APT = 2, BPT = 4;
  u16* AhS = smem;
  u16* AlS = smem + 4096;
  u16* BhS = smem + 8192;
  int tid = threadIdx.x;
  int l = tid & 63, w = tid >> 6;
  int wm = (w >> 1) * 32, wn = (w & 1) * 64;
  u16x8 rAh[APT], rAl[PA ? APT : 1], rBh[BPT];
  f32x4 acc[2][4] = {};
#define LOADTILE(kb_)                                                               \
  {                                                                                 \
    _Pragma("unroll") for (int p = 0; p < APT; ++p) {                               \
      int idx = tid + p * 256;                                                      \
      int row = idx >> 3, cc = idx & 7;                                             \
      rAh[p] = *(const u16x8*)&Ah[(size_t)(bm + row) * K + (kb_) + cc * 8];         \
      if (PA) rAl[p] = *(const u16x8*)&Al[(size_t)(bm + row) * K + (kb_) + cc * 8]; \
    }                                                                               \
    _Pragma("unroll") for (int p = 0; p < BPT; ++p) {                               \
      int idx = tid + p * 256;                                                      \
      int row = idx >> 3, cc = idx & 7;                                             \
      rBh[p] = *(const u16x8*)&Bh[(size_t)(bn + row) * K + (kb_) + cc * 8];         \
    }                                                                               \
  }
  LOADTILE(0)
  for (int kb = 0; kb < K; kb += 64) {
    __syncthreads();
#pragma unroll
    for (int p = 0; p < APT; ++p) {
      int idx = tid + p * 256;
      int row = idx >> 3, cc = idx & 7;
      int off = row * 64 + ((cc * 8) ^ ((row & 7) << 3));
      *(u16x8*)&AhS[off] = rAh[p];
      if (PA) *(u16x8*)&AlS[off] = rAl[p];
    }
#pragma unroll
    for (int p = 0; p < BPT; ++p) {
      int idx = tid + p * 256;
      int row = idx >> 3, cc = idx & 7;
      int off = row * 64 + ((cc * 8) ^ ((row & 7) << 3));
      *(u16x8*)&BhS[off] = rBh[p];
    }
    if (kb + 64 < K) LOADTILE(kb + 64)
    __syncthreads();
    __builtin_amdgcn_s_setprio(1);
#pragma unroll
    for (int sl = 0; sl < 2; ++sl) {
      short8v fa[2], fal[2], fb[4];
      int kof = (l >> 4) * 8 + sl * 32;
#pragma unroll
      for (int m = 0; m < 2; ++m) {
        int row = wm + m * 16 + (l & 15);
        int off = row * 64 + (kof ^ ((row & 7) << 3));
        fa[m] = *(const short8v*)&AhS[off];
        if (PA) fal[m] = *(const short8v*)&AlS[off];
      }
#pragma unroll
      for (int n = 0; n < 4; ++n) {
        int row = wn + n * 16 + (l & 15);
        int off = row * 64 + (kof ^ ((row & 7) << 3));
        fb[n] = *(const short8v*)&BhS[off];
      }
#pragma unroll
      for (int m = 0; m < 2; ++m)
#pragma unroll
        for (int n = 0; n < 4; ++n) {
          acc[m][n] = __builtin_amdgcn_mfma_f32_16x16x32_bf16(fa[m], fb[n], acc[m][n], 0, 0, 0);
          if (PA)
            acc[m][n] = __builtin_amdgcn_mfma_f32_16x16x32_bf16(fal[m], fb[n], acc[m][n], 0, 0, 0);
        }
    }
    __builtin_amdgcn_s_setprio(0);
  }
#undef LOADTILE
#pragma unroll
  for (int m = 0; m < 2; ++m)
#pragma unroll
    for (int n = 0; n < 4; ++n)
#pragma unroll
      for (int r = 0; r < 4; ++r) {
        int grow = bm + wm + m * 16 + (l >> 4) * 4 + r;
        int gcol = bn + wn + n * 16 + (l & 15);
        float v = acc[m][n][r];
        if (MODE == 0) {
          C[(size_t)grow * N + gcol] = v;
        } else if (MODE == 1) {
          u16 hb = f2bf(v);
          O1[(size_t)grow * N + gcol] = hb;
          O2[(size_t)grow * N + gcol] = f2bf(v - bf2f(hb));
        } else {
          int k = gcol & 31;
          int gp = (gcol & ~31) | (((k >> 2) & 3) << 3) |
                   (((k >> 4) & 1) << 2) | (k & 3);
          O1[(size_t)grow * N + gp] = f2bf(v);
        }
      }
}

// ---------------- fused QKV projections (r16, verified) ----------------
__global__ __launch_bounds__(256, 1) void qkv_mega(
    const u16* __restrict__ Xqh, const u16* __restrict__ Xql, const u16* __restrict__ Wq,
    const u16* __restrict__ Xkh, const u16* __restrict__ Xkl, const u16* __restrict__ Wk,
    const u16* __restrict__ Xvh, const u16* __restrict__ Vwh,
    u16* __restrict__ Qh, u16* __restrict__ Ql,
    u16* __restrict__ Kh, u16* __restrict__ Kl,
    u16* __restrict__ Vt) {
  __shared__ __align__(16) u16 SMEM[16384];   // 32KB
  int bx = blockIdx.x;
  if (bx < 512) {
    int bm = (bx >> 3) * 64, bn = (bx & 7) * 128;
    gemm_body<true, 1>(Xqh, Xql, Wq, 1024, 1024, bm, bn, nullptr, Qh, Ql, SMEM);
  } else if (bx < 640) {
    int t = bx - 512;
    int bm = (t >> 1) * 64, bn = (t & 1) * 128;
    gemm_body<true, 1>(Xkh, Xkl, Wk, 256, 1024, bm, bn, nullptr, Kh, Kl, SMEM);
  } else {
    int t = bx - 640;
    int bm = (t >> 5) * 64, bn = (t & 31) * 128;
    gemm_body<false, 3>(Vwh, nullptr, Xvh, 4096, 1024, bm, bn, nullptr, Vt, nullptr, SMEM);
  }
}

// ---------------- O-projection GEMM (MODE 0, 1-pass) ----------------
__global__ __launch_bounds__(256, 1) void o_gemm(
    const u16* __restrict__ Ah, const u16* __restrict__ Bh,
    float* __restrict__ C) {
  __shared__ __align__(16) u16 SMEM[16384];
  int bm = blockIdx.y * 64, bn = blockIdx.x * 128;
  gemm_body<false, 0>(Ah, nullptr, Bh, 1024, 1024, bm, bn, C, nullptr, nullptr, SMEM);
}

// ---------------- split-K attention PHASE 1: gload_lds + defer-max (T13) ----------------
__global__ __launch_bounds__(256, 3) void attn_part(
    const u16* __restrict__ Qh, const u16* __restrict__ Ql,
    const u16* __restrict__ Kh, const u16* __restrict__ Kl,
    const u16* __restrict__ Vt,
    const float* __restrict__ qk_gain,
    u16* __restrict__ Opart, float* __restrict__ MLpart) {
  __shared__ __align__(16) u16 SM[24576];   // 2 x (Kh|Kl|Vt 4096 u16 each) = 48KB
  int tid = threadIdx.x;
  int w = tid >> 6, l = tid & 63;
  int hb = blockIdx.x;
  int h = hb & 15, b = hb >> 4;
  int kvh = h >> 2;
  int f = blockIdx.y;                 // 0..23
  int qt = C_QT[f];
  int s0 = C_S0[f];
  int s1 = s0 + C_NS[f];
  int q0 = qt * 128;
  const float sc2 = qk_gain[0] * 0.125f * 1.44269504f;
  const float thr = 8.0f / sc2;       // defer-max threshold (P <= 2^8)
#define GLOADTILE(K0, BI)                                                       \
  {                                                                             \
    u16* bb = SM + (BI) * 12288;                                                \
    _Pragma("unroll") for (int p = 0; p < 2; ++p) {                             \
      int idx = tid + p * 256;                                                  \
      int jj = idx >> 3;                                                        \
      int cc = (idx & 7) ^ (jj & 7);                                            \
      size_t kb = ((size_t)(b * Tc + (K0) + jj)) * (HKVc * HDc) + kvh * 64 + cc * 8; \
      size_t vb = ((size_t)(kvh * 64 + jj)) * (size_t)Mc + b * Tc + (K0) + cc * 8;   \
      u16* l0 = bb + (w * 64 + p * 256) * 8;                                    \
      gload_lds16(&Kh[kb], l0);                                                 \
      gload_lds16(&Kl[kb], l0 + 4096);                                          \
      gload_lds16(&Vt[vb], l0 + 8192);                                          \
    }                                                                           \
  }
  short8v qb_h[4], qb_l[4];
#pragma unroll
  for (int qp = 0; qp < 2; ++qp) {
    size_t qrow = (size_t)(b * Tc + q0 + w * 32 + qp * 16 + (l & 15));
#pragma unroll
    for (int sl = 0; sl < 2; ++sl) {
      int dstart = (l >> 4) * 8 + sl * 32;
      qb_h[qp * 2 + sl] = *(const short8v*)&Qh[qrow * Dc + h * 64 + dstart];
      qb_l[qp * 2 + sl] = *(const short8v*)&Ql[qrow * Dc + h * 64 + dstart];
    }
  }
  f32x4 Oacc[8] = {{0,0,0,0},{0,0,0,0},{0,0,0,0},{0,0,0,0},
                   {0,0,0,0},{0,0,0,0},{0,0,0,0},{0,0,0,0}};
  float mrow[2] = {-3.0e38f, -3.0e38f};
  float lrow[2] = {0.f, 0.f};
  int qmax_w = q0 + w * 32 + 31;
  GLOADTILE(s0 * 64, 0)
  GLOADTILE((s0 + 1) * 64, 1)
  __syncthreads();
  for (int li = 0; li < s1 - s0; ++li) {
    int stp = s0 + li;
    int k0 = stp * 64;
    u16* Kh_s = SM + (li & 1) * 12288;
    u16* Kl_s = Kh_s + 4096;
    u16* Vt_s = Kh_s + 8192;
    if (k0 <= qmax_w) {
      f32x4 s[8] = {{0,0,0,0},{0,0,0,0},{0,0,0,0},{0,0,0,0},
                    {0,0,0,0},{0,0,0,0},{0,0,0,0},{0,0,0,0}};
      __builtin_amdgcn_s_setprio(1);
#pragma unroll
      for (int kt = 0; kt < 4; ++kt) {
        int key = kt * 16 + (l & 15);
#pragma unroll
        for (int sl = 0; sl < 2; ++sl) {
          int dstart = ((l >> 4) * 8 + 32 * sl) ^ ((key & 7) << 3);
          short8v bh = *(const short8v*)&Kh_s[key * 64 + dstart];
          short8v bl = *(const short8v*)&Kl_s[key * 64 + dstart];
#pragma unroll
          for (int qp = 0; qp < 2; ++qp) {
            s[qp * 4 + kt] = __builtin_amdgcn_mfma_f32_16x16x32_bf16(bh, qb_h[qp * 2 + sl], s[qp * 4 + kt], 0, 0, 0);
            s[qp * 4 + kt] = __builtin_amdgcn_mfma_f32_16x16x32_bf16(bl, qb_h[qp * 2 + sl], s[qp * 4 + kt], 0, 0, 0);
            s[qp * 4 + kt] = __builtin_amdgcn_mfma_f32_16x16x32_bf16(bh, qb_l[qp * 2 + sl], s[qp * 4 + kt], 0, 0, 0);
          }
        }
      }
      __builtin_amdgcn_s_setprio(0);
      bool full = (k0 + 63) <= (q0 + w * 32);
      if (!full) {
#pragma unroll
        for (int qp = 0; qp < 2; ++qp) {
          int qg = q0 + w * 32 + qp * 16 + (l & 15);
#pragma unroll
          for (int kt = 0; kt < 4; ++kt)
#pragma unroll
            for (int r = 0; r < 4; ++r)
              if (k0 + kt * 16 + ((l >> 4) << 2) + r > qg) s[qp * 4 + kt][r] = -3.0e38f;
        }
      }
      float p[2][4][4];
#pragma unroll
      for (int qp = 0; qp < 2; ++qp) {
        float mk[4];
#pragma unroll
        for (int kt = 0; kt < 4; ++kt)
          mk[kt] = fmaxf(fmaxf(s[qp * 4 + kt][0], s[qp * 4 + kt][1]),
                         fmaxf(s[qp * 4 + kt][2], s[qp * 4 + kt][3]));
        float mx = fmaxf(fmaxf(mk[0], mk[1]), fmaxf(mk[2], mk[3]));
        mx = fmaxf(mx, __shfl_xor(mx, 16));
        mx = fmaxf(mx, __shfl_xor(mx, 32));
        if (!__all(mx - mrow[qp] <= thr)) {
          float mnew = fmaxf(mrow[qp], mx);
          float corr = fast_exp2((mrow[qp] - mnew) * sc2);
          mrow[qp] = mnew;
          lrow[qp] *= corr;
#pragma unroll
          for (int dt = 0; dt < 4; ++dt) Oacc[qp * 4 + dt] *= corr;
        }
        float msc = mrow[qp] * sc2;
        float sk[4];
#pragma unroll
        for (int kt = 0; kt < 4; ++kt) {
#pragma unroll
          for (int r = 0; r < 4; ++r)
            p[qp][kt][r] = fast_exp2(__builtin_fmaf(s[qp * 4 + kt][r], sc2, -msc));
          sk[kt] = (p[qp][kt][0] + p[qp][kt][1]) + (p[qp][kt][2] + p[qp][kt][3]);
        }
        float rs = (sk[0] + sk[1]) + (sk[2] + sk[3]);
        rs += __shfl_xor(rs, 16);
        rs += __shfl_xor(rs, 32);
        lrow[qp] += rs;
      }
      short8v fbv[4];
#pragma unroll
      for (int qp = 0; qp < 2; ++qp)
#pragma unroll
        for (int sl = 0; sl < 2; ++sl) {
          union { u32 u[4]; short8v v; } fq;
          fq.u[0] = cvt_pk_bf16(p[qp][2 * sl][0], p[qp][2 * sl][1]);
          fq.u[1] = cvt_pk_bf16(p[qp][2 * sl][2], p[qp][2 * sl][3]);
          fq.u[2] = cvt_pk_bf16(p[qp][2 * sl + 1][0], p[qp][2 * sl + 1][1]);
          fq.u[3] = cvt_pk_bf16(p[qp][2 * sl + 1][2], p[qp][2 * sl + 1][3]);
          fbv[qp * 2 + sl] = fq.v;
        }
      __builtin_amdgcn_s_setprio(1);
#pragma unroll
      for (int dt = 0; dt < 4; ++dt) {
        int d = dt * 16 + (l & 15);
#pragma unroll
        for (int sl = 0; sl < 2; ++sl) {
          int kstart = ((l >> 4) * 8 + 32 * sl) ^ ((d & 7) << 3);
          short8v fav = *(const short8v*)&Vt_s[d * 64 + kstart];
#pragma unroll
          for (int qp = 0; qp < 2; ++qp)
            Oacc[qp * 4 + dt] = __builtin_amdgcn_mfma_f32_16x16x32_bf16(fav, fbv[qp * 2 + sl], Oacc[qp * 4 + dt], 0, 0, 0);
        }
      }
      __builtin_amdgcn_s_setprio(0);
    }
    __syncthreads();   // readers of buf[li&1] done; in-flight DMA drained
    if (stp + 2 < s1) GLOADTILE((stp + 2) * 64, li & 1)
  }
  // epilogue: unnormalized partial O (bf16) + per-q m,l
  int G = hb * 24 + f;
  u16* Op = Opart + (size_t)G * 8192;           // [128 q][64 d]
  float* Es = (float*)SM + w * 1088;            // per-wave [16 q][68 d]
#pragma unroll
  for (int qp = 0; qp < 2; ++qp) {
#pragma unroll
    for (int dt = 0; dt < 4; ++dt)
#pragma unroll
      for (int r = 0; r < 4; ++r)
        Es[(l & 15) * 68 + dt * 16 + ((l >> 4) << 2) + r] = Oacc[qp * 4 + dt][r];
    int qloc = w * 32 + qp * 16 + (l >> 2);
#pragma unroll
    for (int j = 0; j < 4; ++j) {
      float4 vv = *(const float4*)&Es[(l >> 2) * 68 + (l & 3) * 4 + j * 16];
      u16x4 o4;
      o4[0] = f2bf(vv.x); o4[1] = f2bf(vv.y); o4[2] = f2bf(vv.z); o4[3] = f2bf(vv.w);
      *(u16x4*)&Op[qloc * 64 + (l & 3) * 4 + j * 16] = o4;
    }
  }
  if (l < 16) {
#pragma unroll
    for (int qp = 0; qp < 2; ++qp) {
      int qloc = w * 32 + qp * 16 + l;
      MLpart[(size_t)G * 256 + qloc * 2 + 0] = mrow[qp];
      MLpart[(size_t)G * 256 + qloc * 2 + 1] = lrow[qp];
    }
  }
#undef GLOADTILE
}

// ---------------- PHASE 2: fused merge + RMSNorm + o_g scale -> Xoh bf16 ----------------
__global__ __launch_bounds__(256) void merge_rms(const u16* __restrict__ Opart,
                                                 const float* __restrict__ MLpart,
                                                 const float* __restrict__ o_g,
                                                 const float* __restrict__ qk_gain,
                                                 u16* __restrict__ Xoh) {
  const float sc2 = qk_gain[0] * 0.125f * 1.44269504f;
  int t = threadIdx.x;
  int row_i = t >> 6, l = t & 63;
  int rr = blockIdx.x * 4 + row_i;
  int b = rr >> 11, tpos = rr & 2047;
  int qt = tpos >> 7, qloc = tpos & 127;
  int head = l >> 2;
  int hb = b * 16 + head;
  int nc = (qt >= 8) ? 2 : 1;
  size_t G0 = (size_t)hb * 24 + C_MF[qt * 2 + 0];
  size_t G1 = (size_t)hb * 24 + C_MF[qt * 2 + 1];
  float m0 = MLpart[G0 * 256 + qloc * 2 + 0];
  float l0 = MLpart[G0 * 256 + qloc * 2 + 1];
  float m1 = -3.0e38f, l1 = 0.0f;
  if (nc == 2) {
    m1 = MLpart[G1 * 256 + qloc * 2 + 0];
    l1 = MLpart[G1 * 256 + qloc * 2 + 1];
  }
  float M = fmaxf(m0, m1);
  float w0 = fast_exp2((m0 - M) * sc2);
  float w1 = (nc == 2) ? fast_exp2((m1 - M) * sc2) : 0.0f;
  float L = w0 * l0 + w1 * l1;
  int dio = (l & 3) * 16;   // d-offset within head
  const u16* Op0 = Opart + G0 * 8192 + qloc * 64 + dio;
  float val[16];
  {
    u16x8 a0 = *(const u16x8*)&Op0[0];
    u16x8 a1 = *(const u16x8*)&Op0[8];
#pragma unroll
    for (int j = 0; j < 8; ++j) { val[j] = w0 * bf2f(a0[j]); val[8 + j] = w0 * bf2f(a1[j]); }
  }
  if (nc == 2) {
    const u16* Op1 = Opart + G1 * 8192 + qloc * 64 + dio;
    u16x8 a0 = *(const u16x8*)&Op1[0];
    u16x8 a1 = *(const u16x8*)&Op1[8];
#pragma unroll
    for (int j = 0; j < 8; ++j) { val[j] += w1 * bf2f(a0[j]); val[8 + j] += w1 * bf2f(a1[j]); }
  }
  float invL = 1.0f / L;
#pragma unroll
  for (int j = 0; j < 16; ++j) val[j] *= invL;
  float ss = 0.0f;
#pragma unroll
  for (int j = 0; j < 16; ++j) ss += val[j] * val[j];
#pragma unroll
  for (int off = 1; off < 64; off <<= 1) ss += __shfl_xor(ss, off);
  float inv = 1.0f / sqrtf(ss * (1.0f / (float)Dc) + EPSc);
  int col = head * 64 + dio;
  u16x8 h0, h1;
#pragma unroll
  for (int j = 0; j < 8; ++j) {
    h0[j] = f2bf(val[j] * inv * o_g[col + j]);
    h1[j] = f2bf(val[8 + j] * inv * o_g[col + 8 + j]);
  }
  u16* dst = Xoh + (size_t)rr * Dc + col;
  *(u16x8*)&dst[0] = h0;
  *(u16x8*)&dst[8] = h1;
}

// ---------------- launch ----------------
extern "C" void kernel_launch(void* const* d_in, const int* in_sizes, int n_in,
                              void* d_out, int out_size, void* d_ws, size_t ws_size,
                              hipStream_t stream) {
  const float* x    = (const float*)d_in[0];
  const float* q_w  = (const float*)d_in[1];
  const float* q_g  = (const float*)d_in[2];
  const float* k_w  = (const float*)d_in[3];
  const float* k_g  = (const float*)d_in[4];
  const float* v_w  = (const float*)d_in[5];
  const float* o_w  = (const float*)d_in[6];
  const float* o_g  = (const float*)d_in[7];
  const float* qk_g = (const float*)d_in[8];

  // workspace (bytes), peak ~67.1 MB.  Overlay happens-before chain (all launch-ordered):
  //  - Xqh..Xvh (0..40MB) dead after qkv_mega
  //  - Opart (16..28MB) + MLpart (28..29MB) written by attn_part (post-qkv_mega)
  //  - Xoh (0..8MB, over Xqh) written by merge_rms (post-attn_part; disjoint from Opart)
  char* base = (char*)d_ws;
  u16* Xqh = (u16*)(base + (0ull  << 20));       // 8MB
  u16* Xql = (u16*)(base + (8ull  << 20));       // 8MB
  u16* Xkh = (u16*)(base + (16ull << 20));       // 8MB
  u16* Xkl = (u16*)(base + (24ull << 20));       // 8MB
  u16* Xvh = (u16*)(base + (32ull << 20));       // 8MB
  u16* Qh  = (u16*)(base + (40ull << 20));       // 8MB dedicated
  u16* Ql  = (u16*)(base + (48ull << 20));       // 8MB dedicated
  u16* Kh  = (u16*)(base + (56ull << 20));       // 2MB
  u16* Kl  = (u16*)(base + (58ull << 20));       // 2MB
  u16* Vt  = (u16*)(base + (60ull << 20));       // 2MB
  u16* Wq  = (u16*)(base + (62ull << 20));       // 2MB
  u16* Wk  = (u16*)(base + (64ull << 20));       // 0.5MB
  u16* Wo  = (u16*)(base + (64ull << 20) + (512ull << 10));   // 2MB
  u16* Vwh = (u16*)(base + (66ull << 20) + (512ull << 10));   // 0.5MB
  float* leaf = (float*)(base + (67ull << 20));  // 18432 floats
  float* th   = leaf + 18432;                    // 3
  // overlays
  u16*  Opart   = (u16*)(base + (16ull << 20));  // 12MB: 768 chunks x 16KB (over Xkh/half-Xkl)
  float* MLpart = (float*)(base + (28ull << 20));// 768KB (over rest of Xkl)
  u16*  Xoh     = (u16*)base;                    // 8MB over Xqh (dead after qkv_mega)

  // 1) numpy-exact fp32 thresholds
  np_leafsum_all<<<576, 256, 0, stream>>>(q_w, k_w, o_w, leaf);
  np_treemean3<<<3, 256, 0, stream>>>(leaf, th);

  // 2+3) fused prep: ternary quantize + v_w cast + RMSNorm splits (one launch)
  prep_mega<<<6656, 256, 0, stream>>>(q_w, k_w, o_w, v_w, th, Wq, Wk, Wo, Vwh,
                                      x, q_g, k_g, Xqh, Xql, Xkh, Xkl, Xvh);

  // 4) fused Q+K+V projections (one launch, 768 blocks)
  qkv_mega<<<768, 256, 0, stream>>>(Xqh, Xql, Wq, Xkh, Xkl, Wk, Xvh, Vwh,
                                    Qh, Ql, Kh, Kl, Vt);

  // 5) split-K attention: balanced chunks + gload_lds staging + defer-max
  attn_part<<<dim3(32, 24), 256, 0, stream>>>(Qh, Ql, Kh, Kl, Vt, qk_g, Opart, MLpart);

  // 6) fused merge + RMSNorm + o_g -> Xoh bf16
  merge_rms<<<1024, 256, 0, stream>>>(Opart, MLpart, o_g, qk_g, Xoh);

  // 7) output GEMM -> d_out fp32
  o_gemm<<<dim3(8, 64), 256, 0, stream>>>(Xoh, Wo, (float*)d_out);
}